// Round 21
// baseline (121.342 us; speedup 1.0000x reference)
//
#include <hip/hip_runtime.h>
#include <math.h>

// SAE hierarchical, R21: ROWS=32, 16-wave blocks -- double arithmetic
// intensity of the weight stream. R20 verdict: packed layout + in-body load
// batch + (8,8) = 118.8us (prefetch was spill-bait; deleted). Remaining
// inefficiency: each block read all 768KB weights for only 16 rows. R21:
// 32 rows/block, wave owns a 16-feature slice (2 packed frag loads + 1 bias)
// applied to TWO row tiles (4 MFMAs) -> MFMA:VMEM doubles, chip L2 weight
// traffic halves. 512 blocks x 1024 thr = 2 blocks/CU x 16 waves = 32
// waves/CU (100%); LDS 45.7KB x 2 = 91KB. Weights repacked for the 16-wave
// mapping (pure permutation, values bit-identical). Rescue: 16 waves x 2
// rows, machinery unchanged (selection exact; decode order immaterial at
// bf16 output granularity).

#define D64   64
#define ROWS  32
#define CAP   128
#define FTILE 256
#define HID1  4096
#define HID2  2048
#define K1    32
#define K2    16

typedef __attribute__((ext_vector_type(8))) short bf16x8;
typedef __attribute__((ext_vector_type(4))) float f32x4;
typedef unsigned long long u64;

__device__ __forceinline__ unsigned short f2bf(float f) {
    unsigned u = __float_as_uint(f);
    return (unsigned short)((u + 0x7FFFu + ((u >> 16) & 1u)) >> 16);
}

__device__ __forceinline__ float wave_sum_f32(float v) {
#pragma unroll
    for (int off = 32; off > 0; off >>= 1) v += __shfl_xor(v, off, 64);
    return v;
}

// prep: W1|W2 fp32 -> bf16, packed for 16-wave mapping.
// level L, pass p (256 feats), wave wu (16 feats), frag in {0,1} (k 0-31 /
// 32-63): dst halfword = Lbase + ((p*16+wu)*2+frag)*512 + (g*16+l15)*8,
// content = W row (p*256+wu*16+l15), halfwords [k8*8, k8*8+8), g=k8&3,
// frag = (k8>=4).
__global__ __launch_bounds__(256) void prep_w(const float* __restrict__ W1,
                                              const float* __restrict__ W2,
                                              unsigned short* __restrict__ wh) {
    const int t = blockIdx.x * 256 + threadIdx.x;    // 49152 threads, 8 floats each
    const int fg = t >> 3;                           // global feature 0..6143
    const int k8 = t & 7;                            // 8-halfword chunk
    const int lvl = (fg >= HID1);
    const int f = lvl ? fg - HID1 : fg;
    const float* src = lvl ? (W2 + (size_t)f * D64) : (W1 + (size_t)f * D64);
    const int p = f >> 8, rem = f & 255;
    const int wu = rem >> 4, l15 = rem & 15;
    const int frag = (k8 >= 4) ? 1 : 0;
    const int g = k8 & 3;
    float4 a = ((const float4*)src)[k8 * 2];
    float4 b = ((const float4*)src)[k8 * 2 + 1];
    u64 pk0 = (u64)f2bf(a.x) | ((u64)f2bf(a.y) << 16)
            | ((u64)f2bf(a.z) << 32) | ((u64)f2bf(a.w) << 48);
    u64 pk1 = (u64)f2bf(b.x) | ((u64)f2bf(b.y) << 16)
            | ((u64)f2bf(b.z) << 32) | ((u64)f2bf(b.w) << 48);
    const size_t dst = (size_t)(lvl ? HID1 * D64 : 0)
                     + (size_t)(((p * 16 + wu) * 2 + frag) * 512 + (g * 16 + l15) * 8);
    *(u64*)&wh[dst]     = pk0;
    *(u64*)&wh[dst + 4] = pk1;
}

__global__ __launch_bounds__(1024)
__attribute__((amdgpu_waves_per_eu(8, 8)))
void sae_hier_mfma(
    const float* __restrict__ x,
    const float* __restrict__ W1,  const float* __restrict__ b1,
    const float* __restrict__ Wd1, const float* __restrict__ bd1,
    const float* __restrict__ W2,  const float* __restrict__ b2,
    const float* __restrict__ Wd2, const float* __restrict__ bd2,
    const unsigned short* __restrict__ wh,
    float* __restrict__ out)
{
    __shared__ uint2 s_buf[ROWS * CAP];                       // 32 KB candidates
    __shared__ __align__(16) float s_xf32[ROWS * D64];        // 8 KB exact input
    __shared__ __align__(16) unsigned short s_ah[ROWS * D64]; // 4 KB bf16 A (linear)
    __shared__ float s_sig[ROWS];
    __shared__ float s_thr[ROWS];
    __shared__ float s_scale[ROWS];
    __shared__ int   s_cnt[ROWS];
    __shared__ int   s_act[ROWS];
    __shared__ int   s_anybad;

    const int tid  = threadIdx.x;
    const int lane = tid & 63;
    const int wu   = __builtin_amdgcn_readfirstlane(tid >> 6);  // 16 waves
    const int rowbase = blockIdx.x * ROWS;
    const int g   = lane >> 4;
    const int l15 = lane & 15;

    if (tid < ROWS) { s_cnt[tid] = 0; s_scale[tid] = 1.0f; s_act[tid] = 1; }

    // ---- stage (x - b_dec): fp32 exact + bf16 linear + threshold base ----
    if (tid < 512) {
        const int r = tid >> 4, q = tid & 15;                 // 32 rows x 16 quads
        float4 a = ((const float4*)x)[(size_t)(rowbase + r) * 16 + q];
        float4 b = ((const float4*)bd1)[q];
        float4 v = make_float4(a.x - b.x, a.y - b.y, a.z - b.z, a.w - b.w);
        ((float4*)s_xf32)[r * 16 + q] = v;
        u64 pk = (u64)f2bf(v.x) | ((u64)f2bf(v.y) << 16)
               | ((u64)f2bf(v.z) << 32) | ((u64)f2bf(v.w) << 48);
        *(u64*)&s_ah[(r * 16 + q) * 4] = pk;
        float ss = fmaf(v.x, v.x, fmaf(v.y, v.y, fmaf(v.z, v.z, v.w * v.w)));
        ss += __shfl_xor(ss, 1, 64); ss += __shfl_xor(ss, 2, 64);
        ss += __shfl_xor(ss, 4, 64); ss += __shfl_xor(ss, 8, 64);
        if (q == 0) s_sig[r] = 0.25f * sqrtf(ss);             // 2*sigma = ||.||/4
    }

// push 4 rows' values for one accumulator; RB = row base, TA..TD thresholds
#define PUSHT(ACC, BIAS, COLG, RB, TA, TB, TC, TD) { \
    float v0 = fmaxf(ACC[0] + (BIAS), 0.f); \
    float v1 = fmaxf(ACC[1] + (BIAS), 0.f); \
    float v2 = fmaxf(ACC[2] + (BIAS), 0.f); \
    float v3 = fmaxf(ACC[3] + (BIAS), 0.f); \
    if (v0 > TA) { int s = atomicAdd(&s_cnt[(RB)+0], 1); if (s < CAP) s_buf[((RB)+0)*CAP+s] = make_uint2(__float_as_uint(v0), (unsigned)(COLG)); } \
    if (v1 > TB) { int s = atomicAdd(&s_cnt[(RB)+1], 1); if (s < CAP) s_buf[((RB)+1)*CAP+s] = make_uint2(__float_as_uint(v1), (unsigned)(COLG)); } \
    if (v2 > TC) { int s = atomicAdd(&s_cnt[(RB)+2], 1); if (s < CAP) s_buf[((RB)+2)*CAP+s] = make_uint2(__float_as_uint(v2), (unsigned)(COLG)); } \
    if (v3 > TD) { int s = atomicAdd(&s_cnt[(RB)+3], 1); if (s < CAP) s_buf[((RB)+3)*CAP+s] = make_uint2(__float_as_uint(v3), (unsigned)(COLG)); } }

#pragma unroll 1
    for (int level = 0; level < 2; ++level) {
        const float* We  = level ? W2  : W1;
        const float* be  = level ? b2  : b1;
        const float* Wd  = level ? Wd2 : Wd1;
        const float* bdv = level ? bd2 : bd1;
        const unsigned short* whL = wh + (level ? (size_t)HID1 * D64 : 0);
        const int KSEL   = level ? K2 : K1;
        const int NPASS  = (level ? HID2 : HID1) / FTILE;

        __syncthreads();

        // ==== approx GEMM: 16-feature slice x two row tiles per pass ====
#pragma unroll 1
        for (int attempt = 0; attempt < 8; ++attempt) {
            if (tid < ROWS) s_thr[tid] = s_act[tid] ? s_sig[tid] * s_scale[tid] : 3.4e38f;
            __syncthreads();
            bf16x8 a0 = *(const bf16x8*)&s_ah[l15 * D64 + 8 * g];
            bf16x8 a1 = *(const bf16x8*)&s_ah[l15 * D64 + 32 + 8 * g];
            bf16x8 a2 = *(const bf16x8*)&s_ah[(16 + l15) * D64 + 8 * g];
            bf16x8 a3 = *(const bf16x8*)&s_ah[(16 + l15) * D64 + 32 + 8 * g];
            const float t0 = s_thr[g * 4 + 0], t1 = s_thr[g * 4 + 1];
            const float t2 = s_thr[g * 4 + 2], t3 = s_thr[g * 4 + 3];
            const float t4 = s_thr[16 + g * 4 + 0], t5 = s_thr[16 + g * 4 + 1];
            const float t6 = s_thr[16 + g * 4 + 2], t7 = s_thr[16 + g * 4 + 3];

#pragma unroll 1
            for (int p = 0; p < NPASS; ++p) {
                const unsigned short* wb = whL + (size_t)(p * 16 + wu) * 1024;
                const int fbase = p * FTILE + wu * 16 + l15;
                // batch: 2 packed fragment loads + 1 bias load in flight
                bf16x8 c00 = *(const bf16x8*)&wb[lane * 8];
                bf16x8 c01 = *(const bf16x8*)&wb[512 + lane * 8];
                float bias0 = be[fbase];
                f32x4 acc0 = {0.f, 0.f, 0.f, 0.f}, acc2 = {0.f, 0.f, 0.f, 0.f};
                acc0 = __builtin_amdgcn_mfma_f32_16x16x32_bf16(a0, c00, acc0, 0, 0, 0);
                acc0 = __builtin_amdgcn_mfma_f32_16x16x32_bf16(a1, c01, acc0, 0, 0, 0);
                acc2 = __builtin_amdgcn_mfma_f32_16x16x32_bf16(a2, c00, acc2, 0, 0, 0);
                acc2 = __builtin_amdgcn_mfma_f32_16x16x32_bf16(a3, c01, acc2, 0, 0, 0);
                PUSHT(acc0, bias0, fbase, g * 4, t0, t1, t2, t3)
                PUSHT(acc2, bias0, fbase, 16 + g * 4, t4, t5, t6, t7)
            }
            __syncthreads();
            if (tid == 0) s_anybad = 0;
            __syncthreads();
            if (tid < ROWS) {
                int c = s_cnt[tid];
                bool lo = (c < KSEL), hi = (c > CAP);
                bool bad = (lo || hi) && (attempt < 7);
                s_act[tid] = bad ? 1 : 0;
                if (bad) { s_scale[tid] *= (lo ? 0.85f : 1.15f); s_cnt[tid] = 0; atomicAdd(&s_anybad, 1); }
            }
            __syncthreads();
            if (s_anybad == 0) break;
        }

        // ==== coalesced exact rescue (bit-exact) + radix select + decode ====
        // 16 waves x 2 rows each
#pragma unroll 1
        for (int q2 = 0; q2 < 2; ++q2) {
            const int r = wu * 2 + q2;
            int n = s_cnt[r]; if (n > CAP) n = CAP;
            const int kq = lane & 15;
            const int cg = lane >> 4;
            const float4 xv = ((const float4*)s_xf32)[r * 16 + kq];
#pragma unroll 4
            for (int s = 0; s < n; s += 4) {
                const int sc = s + cg;
                unsigned j = (sc < n) ? s_buf[r * CAP + sc].y : 0u;
                float4 wv = ((const float4*)We)[(size_t)j * 16 + kq];
                float d = fmaf(wv.x, xv.x, fmaf(wv.y, xv.y, fmaf(wv.z, xv.z, wv.w * xv.w)));
                d += __shfl_xor(d, 1, 64); d += __shfl_xor(d, 2, 64);
                d += __shfl_xor(d, 4, 64); d += __shfl_xor(d, 8, 64);
                if (kq == 0 && sc < n)
                    s_buf[r * CAP + sc].x = __float_as_uint(fmaxf(d + be[j], 0.f));
            }
            // keys: (exact valbits << 32) | ~idx  (distinct; low index wins ties)
            u64 k0 = 0ull, k1 = 0ull;
            if (lane < n)      { uint2 pp = s_buf[r * CAP + lane];      k0 = ((u64)pp.x << 32) | (unsigned)(~pp.y); }
            if (lane + 64 < n) { uint2 pp = s_buf[r * CAP + lane + 64]; k1 = ((u64)pp.x << 32) | (unsigned)(~pp.y); }
            // radix select: T = KSEL-th largest key
            u64 T = 0ull;
#pragma unroll 1
            for (int b = 62; b >= 32; --b) {
                u64 cand = T | (1ull << b);
                int c = __popcll(__ballot(k0 >= cand)) + __popcll(__ballot(k1 >= cand));
                if (c >= KSEL) T = cand;
            }
            T |= 0xFFFFF000ull;      // idx < 4096 -> ~idx bits 31..12 always set
#pragma unroll 1
            for (int b = 11; b >= 0; --b) {
                u64 cand = T | (1ull << b);
                int c = __popcll(__ballot(k0 >= cand)) + __popcll(__ballot(k1 >= cand));
                if (c >= KSEL) T = cand;
            }
            // compact exactly-KSEL selected keys into slots [0, KSEL)
            bool f0 = (k0 >= T), f1 = (k1 >= T);
            u64 m0 = __ballot(f0), m1 = __ballot(f1);
            u64 below = (1ull << lane) - 1ull;
            int r0 = __popcll(m0 & below);
            int r1 = __popcll(m0) + __popcll(m1 & below);
            if (f0) s_buf[r * CAP + r0] = make_uint2((unsigned)(k0 >> 32), ~(unsigned)k0);
            if (f1) s_buf[r * CAP + r1] = make_uint2((unsigned)(k1 >> 32), ~(unsigned)k1);
            // decode: rec = bdv + sum z_t * Wd[idx_t] (coalesced row reads)
            float rec = bdv[lane];
#pragma unroll 2
            for (int t = 0; t < KSEL; t += 4) {
                uint2 e0 = s_buf[r * CAP + t + 0];
                uint2 e1 = s_buf[r * CAP + t + 1];
                uint2 e2 = s_buf[r * CAP + t + 2];
                uint2 e3 = s_buf[r * CAP + t + 3];
                float w0 = Wd[(size_t)e0.y * D64 + lane];
                float w1 = Wd[(size_t)e1.y * D64 + lane];
                float w2 = Wd[(size_t)e2.y * D64 + lane];
                float w3 = Wd[(size_t)e3.y * D64 + lane];
                rec = fmaf(__uint_as_float(e0.x), w0, rec);
                rec = fmaf(__uint_as_float(e1.x), w1, rec);
                rec = fmaf(__uint_as_float(e2.x), w2, rec);
                rec = fmaf(__uint_as_float(e3.x), w3, rec);
            }
            if (level == 0) {
                float e = wave_sum_f32(rec * rec);
                if (lane == 0) s_sig[r] = 0.25f * sqrtf(e);   // 2*sigma for level 1
                s_xf32[r * D64 + lane] = rec;                 // exact recon0
                s_ah[r * D64 + lane] = f2bf(rec);             // bf16 A for level 1
            } else {
                float rec0 = s_xf32[r * D64 + lane];
                out[(size_t)(rowbase + r) * D64 + lane] =
                    (1.0f / 1.5f) * rec0 + (0.5f / 1.5f) * rec;
            }
        }
        if (level == 0) {
            __syncthreads();
            if (tid < ROWS) { s_cnt[tid] = 0; s_scale[tid] = 1.0f; s_act[tid] = 1; }
        }
    }
}

extern "C" void kernel_launch(void* const* d_in, const int* in_sizes, int n_in,
                              void* d_out, int out_size, void* d_ws, size_t ws_size,
                              hipStream_t stream) {
    (void)n_in; (void)out_size; (void)ws_size;
    const float* x   = (const float*)d_in[0];
    const float* W1  = (const float*)d_in[1];
    const float* b1  = (const float*)d_in[2];
    const float* Wd1 = (const float*)d_in[3];
    const float* bd1 = (const float*)d_in[4];
    const float* W2  = (const float*)d_in[5];
    const float* b2  = (const float*)d_in[6];
    const float* Wd2 = (const float*)d_in[7];
    const float* bd2 = (const float*)d_in[8];
    unsigned short* wh = (unsigned short*)d_ws;   // 768 KB bf16 packed weights

    // (4096+2048) rows x 8 chunks = 49152 threads
    prep_w<<<(HID1 + HID2) * 8 / 256, 256, 0, stream>>>(W1, W2, wh);

    const int batch = in_sizes[0] / D64;     // 16384
    const int grid  = batch / ROWS;          // 512 blocks, 2/CU x 16 waves = 100%

    sae_hier_mfma<<<grid, 1024, 0, stream>>>(x, W1, b1, Wd1, bd1, W2, b2, Wd2, bd2,
                                             wh, (float*)d_out);
}